// Round 1
// baseline (133.614 us; speedup 1.0000x reference)
//
#include <hip/hip_runtime.h>

#define BB 8
#define CL 4096
#define QL 512
#define DD 256

typedef unsigned short u16;
typedef float f32x4 __attribute__((ext_vector_type(4)));
typedef short s16x8 __attribute__((ext_vector_type(8)));

static __device__ __forceinline__ u16 f2bf(float x) {
  unsigned int u = __float_as_uint(x);
  u += 0x7FFFu + ((u >> 16) & 1u);
  return (u16)(u >> 16);
}
static __device__ __forceinline__ float bf2f(u16 h) {
  return __uint_as_float(((unsigned int)h) << 16);
}

// ---------------- K0: prep q (bf16 row-major, bf16 transposed, qw dots) ----
__global__ __launch_bounds__(256) void prep_q_k(
    const float* __restrict__ q, const float* __restrict__ w,
    u16* __restrict__ qbf, u16* __restrict__ qTbf, float* __restrict__ qw_g)
{
  __shared__ u16 qs[8][256];
  __shared__ float red[8][32];
  int blk = blockIdx.x;
  int b = blk >> 6;
  int j0 = (blk & 63) * 8;
  int t = threadIdx.x;
  int r = t >> 5;
  int cs = (t & 31) * 8;

  const float* qrow = q + ((size_t)(b * QL + j0 + r)) * DD + cs;
  float4 v0 = *(const float4*)(qrow);
  float4 v1 = *(const float4*)(qrow + 4);
  float4 w0 = *(const float4*)(w + cs);       // w_q
  float4 w1 = *(const float4*)(w + cs + 4);
  float pw = v0.x*w0.x + v0.y*w0.y + v0.z*w0.z + v0.w*w0.w
           + v1.x*w1.x + v1.y*w1.y + v1.z*w1.z + v1.w*w1.w;

  union { u16 u[8]; uint4 v; } pk;
  pk.u[0]=f2bf(v0.x); pk.u[1]=f2bf(v0.y); pk.u[2]=f2bf(v0.z); pk.u[3]=f2bf(v0.w);
  pk.u[4]=f2bf(v1.x); pk.u[5]=f2bf(v1.y); pk.u[6]=f2bf(v1.z); pk.u[7]=f2bf(v1.w);

  *(uint4*)(qbf + ((size_t)(b * QL + j0 + r)) * DD + cs) = pk.v;
  *(uint4*)(&qs[r][cs]) = pk.v;
  red[r][t & 31] = pw;
  __syncthreads();

  if (t < 8) {
    float s = 0.f;
    #pragma unroll
    for (int k = 0; k < 32; ++k) s += red[t][k];
    qw_g[b * QL + j0 + t] = s;
  }

  // transpose: thread t owns column d = t, packs 8 j's
  int d = t;
  union { u16 u[8]; uint4 v; } tp;
  #pragma unroll
  for (int jj = 0; jj < 8; ++jj) tp.u[jj] = qs[jj][d];
  *(uint4*)(qTbf + ((size_t)(b * DD + d)) * QL + j0) = tp.v;
}

// ---------------- K1: main fused attention over a 32-row c tile -----------
__global__ __launch_bounds__(256, 2) void attn_main_k(
    const float* __restrict__ c, const float* __restrict__ w,
    const u16* __restrict__ qbf, const u16* __restrict__ qTbf,
    const float* __restrict__ qw_g, float* __restrict__ rowmax_g,
    float* __restrict__ out)
{
  __shared__ u16 cm[32][264];     // c*w_m bf16, padded stride (conflict-ok)
  __shared__ u16 P[32][536];      // normalized softmax probs bf16, padded
  __shared__ float qw_s[QL];
  __shared__ float cw_s[32];
  __shared__ float redc[32][8];
  __shared__ float red_m[4][32];
  __shared__ float red_z[4][32];

  int t = threadIdx.x;
  int blk = blockIdx.x;
  int b = blk >> 7;
  int it0 = (blk & 127) * 32;

  // ---- staging: c tile -> cm bf16 LDS, cw dots, out segment 0 (c copy) ----
  {
    int r = t >> 3;
    int cg = (t & 7) * 32;
    const float* crow = c + ((size_t)(b * CL + it0 + r)) * DD + cg;
    float* outrow = out + ((size_t)(b * CL + it0 + r)) * (4 * DD) + cg;
    float pcw = 0.f;
    #pragma unroll
    for (int u = 0; u < 32; u += 4) {
      float4 cv  = *(const float4*)(crow + u);
      float4 wcv = *(const float4*)(w + DD + cg + u);      // w_c
      float4 wmv = *(const float4*)(w + 2 * DD + cg + u);  // w_m
      *(float4*)(outrow + u) = cv;                         // segment 0
      pcw += cv.x * wcv.x + cv.y * wcv.y + cv.z * wcv.z + cv.w * wcv.w;
      ushort4 hv;
      hv.x = f2bf(cv.x * wmv.x); hv.y = f2bf(cv.y * wmv.y);
      hv.z = f2bf(cv.z * wmv.z); hv.w = f2bf(cv.w * wmv.w);
      *(ushort4*)(&cm[r][cg + u]) = hv;
    }
    redc[r][t & 7] = pcw;
    qw_s[t]       = qw_g[b * QL + t];
    qw_s[t + 256] = qw_g[b * QL + 256 + t];
  }
  __syncthreads();
  if (t < 32) {
    float s = 0.f;
    #pragma unroll
    for (int k = 0; k < 8; ++k) s += redc[t][k];
    cw_s[t] = s;
  }
  __syncthreads();

  int wv = t >> 6;       // wave 0..3 -> j chunk of 128
  int ln = t & 63;
  int lr = ln & 15;
  int lg = ln >> 4;
  int jc = wv * 128;

  // ---- GEMM1: S chunk = cm(32x256) @ q^T, frags streamed from L2 ----
  f32x4 acc[2][8];
  #pragma unroll
  for (int m = 0; m < 2; ++m)
    #pragma unroll
    for (int n = 0; n < 8; ++n) acc[m][n] = (f32x4){0.f, 0.f, 0.f, 0.f};

  const u16* qb = qbf + (size_t)b * QL * DD;
  for (int k = 0; k < 8; ++k) {
    s16x8 a0 = *(const s16x8*)(&cm[lr][k * 32 + lg * 8]);
    s16x8 a1 = *(const s16x8*)(&cm[16 + lr][k * 32 + lg * 8]);
    #pragma unroll
    for (int n = 0; n < 8; ++n) {
      s16x8 bq = *(const s16x8*)(qb + ((size_t)(jc + n * 16 + lr)) * DD + k * 32 + lg * 8);
      acc[0][n] = __builtin_amdgcn_mfma_f32_16x16x32_bf16(a0, bq, acc[0][n], 0, 0, 0);
      acc[1][n] = __builtin_amdgcn_mfma_f32_16x16x32_bf16(a1, bq, acc[1][n], 0, 0, 0);
    }
  }

  // ---- softmax from registers (C/D layout: col=lr, row=lg*4+rr) ----
  float qwv[8];
  #pragma unroll
  for (int n = 0; n < 8; ++n) qwv[n] = qw_s[jc + n * 16 + lr];

  float mrow[2][4], invz[2][4];
  #pragma unroll
  for (int m = 0; m < 2; ++m) {
    #pragma unroll
    for (int rr = 0; rr < 4; ++rr) {
      int row = m * 16 + lg * 4 + rr;
      float cwv = cw_s[row];
      float mx = -1e30f;
      #pragma unroll
      for (int n = 0; n < 8; ++n) {
        float s = acc[m][n][rr] + cwv + qwv[n];
        acc[m][n][rr] = s;
        mx = fmaxf(mx, s);
      }
      mx = fmaxf(mx, __shfl_xor(mx, 1));
      mx = fmaxf(mx, __shfl_xor(mx, 2));
      mx = fmaxf(mx, __shfl_xor(mx, 4));
      mx = fmaxf(mx, __shfl_xor(mx, 8));
      if (lr == 0) red_m[wv][row] = mx;
    }
  }
  __syncthreads();
  #pragma unroll
  for (int m = 0; m < 2; ++m) {
    #pragma unroll
    for (int rr = 0; rr < 4; ++rr) {
      int row = m * 16 + lg * 4 + rr;
      float mr = fmaxf(fmaxf(red_m[0][row], red_m[1][row]),
                       fmaxf(red_m[2][row], red_m[3][row]));
      mrow[m][rr] = mr;
      float s = 0.f;
      #pragma unroll
      for (int n = 0; n < 8; ++n) {
        float e = __expf(acc[m][n][rr] - mr);
        acc[m][n][rr] = e;
        s += e;
      }
      s += __shfl_xor(s, 1);
      s += __shfl_xor(s, 2);
      s += __shfl_xor(s, 4);
      s += __shfl_xor(s, 8);
      if (lr == 0) red_z[wv][row] = s;
    }
  }
  __syncthreads();
  #pragma unroll
  for (int m = 0; m < 2; ++m) {
    #pragma unroll
    for (int rr = 0; rr < 4; ++rr) {
      int row = m * 16 + lg * 4 + rr;
      float z = red_z[0][row] + red_z[1][row] + red_z[2][row] + red_z[3][row];
      invz[m][rr] = 1.0f / z;
      if (wv == 0 && lr == 0) rowmax_g[b * CL + it0 + row] = mrow[m][rr];
      #pragma unroll
      for (int n = 0; n < 8; ++n)
        P[row][jc + n * 16 + lr] = f2bf(acc[m][n][rr] * invz[m][rr]);
    }
  }
  __syncthreads();

  // ---- GEMM2: c2q = P(32x512) @ q(512x256); waves split d in 64s ----
  f32x4 o2[2][4];
  #pragma unroll
  for (int m = 0; m < 2; ++m)
    #pragma unroll
    for (int n = 0; n < 4; ++n) o2[m][n] = (f32x4){0.f, 0.f, 0.f, 0.f};

  const u16* qtb = qTbf + (size_t)b * DD * QL;
  for (int k = 0; k < 16; ++k) {
    s16x8 a0 = *(const s16x8*)(&P[lr][k * 32 + lg * 8]);
    s16x8 a1 = *(const s16x8*)(&P[16 + lr][k * 32 + lg * 8]);
    #pragma unroll
    for (int n = 0; n < 4; ++n) {
      s16x8 bv = *(const s16x8*)(qtb + ((size_t)(wv * 64 + n * 16 + lr)) * QL + k * 32 + lg * 8);
      o2[0][n] = __builtin_amdgcn_mfma_f32_16x16x32_bf16(a0, bv, o2[0][n], 0, 0, 0);
      o2[1][n] = __builtin_amdgcn_mfma_f32_16x16x32_bf16(a1, bv, o2[1][n], 0, 0, 0);
    }
  }

  // ---- epilogue: segments 1 (c2q) and 2 (c*c2q) ----
  #pragma unroll
  for (int m = 0; m < 2; ++m)
    #pragma unroll
    for (int n = 0; n < 4; ++n)
      #pragma unroll
      for (int rr = 0; rr < 4; ++rr) {
        int row = it0 + m * 16 + lg * 4 + rr;
        int dcol = wv * 64 + n * 16 + lr;
        float c2q = o2[m][n][rr];
        float cv = c[((size_t)(b * CL + row)) * DD + dcol];
        size_t ob = ((size_t)(b * CL + row)) * (4 * DD);
        out[ob + DD + dcol] = c2q;
        out[ob + 2 * DD + dcol] = cv * c2q;
      }
}

// ---------------- K2: b_attn = softmax_i(rowmax) --------------------------
__global__ __launch_bounds__(256) void battn_k(
    const float* __restrict__ rowmax, float* __restrict__ battn)
{
  __shared__ float rm[4];
  __shared__ float rz[4];
  int b = blockIdx.x;
  int t = threadIdx.x;
  float v[16];
  float mx = -1e30f;
  #pragma unroll
  for (int u = 0; u < 16; ++u) {
    v[u] = rowmax[b * CL + u * 256 + t];
    mx = fmaxf(mx, v[u]);
  }
  #pragma unroll
  for (int o = 1; o < 64; o <<= 1) mx = fmaxf(mx, __shfl_xor(mx, o));
  if ((t & 63) == 0) rm[t >> 6] = mx;
  __syncthreads();
  float M = fmaxf(fmaxf(rm[0], rm[1]), fmaxf(rm[2], rm[3]));
  float e[16];
  float s = 0.f;
  #pragma unroll
  for (int u = 0; u < 16; ++u) { e[u] = __expf(v[u] - M); s += e[u]; }
  #pragma unroll
  for (int o = 1; o < 64; o <<= 1) s += __shfl_xor(s, o);
  if ((t & 63) == 0) rz[t >> 6] = s;
  __syncthreads();
  float Z = rz[0] + rz[1] + rz[2] + rz[3];
  float inv = 1.0f / Z;
  #pragma unroll
  for (int u = 0; u < 16; ++u) battn[b * CL + u * 256 + t] = e[u] * inv;
}

// ---------------- K3: q2c partial reduction over i chunks -----------------
__global__ __launch_bounds__(256) void q2c_partial_k(
    const float* __restrict__ c, const float* __restrict__ battn,
    float* __restrict__ partial)
{
  int blk = blockIdx.x;
  int b = blk >> 5;
  int ch = blk & 31;
  int t = threadIdx.x;
  const float* cb = c + ((size_t)(b * CL + ch * 128)) * DD + t;
  const float* wb = battn + b * CL + ch * 128;
  float acc = 0.f;
  for (int ii = 0; ii < 128; ++ii) acc += wb[ii] * cb[(size_t)ii * DD];
  partial[((size_t)(b * 32 + ch)) * DD + t] = acc;
}

// ---------------- K4: q2c finalize ----------------------------------------
__global__ __launch_bounds__(256) void q2c_final_k(
    const float* __restrict__ partial, float* __restrict__ q2c)
{
  int b = blockIdx.x;
  int t = threadIdx.x;
  float s = 0.f;
  #pragma unroll
  for (int ch = 0; ch < 32; ++ch) s += partial[((size_t)(b * 32 + ch)) * DD + t];
  q2c[b * DD + t] = s;
}

// ---------------- K5: out segment 3 = c * q2c -----------------------------
__global__ __launch_bounds__(256) void seg3_k(
    const float* __restrict__ c, const float* __restrict__ q2c,
    float* __restrict__ out)
{
  size_t stride = (size_t)gridDim.x * 256;
  size_t total = (size_t)BB * CL * (DD / 4);  // float4 count
  for (size_t e = (size_t)blockIdx.x * 256 + threadIdx.x; e < total; e += stride) {
    int b = (int)(e >> 18);            // 4096*64 float4 per batch
    int rem = (int)(e & 262143);
    int i = rem >> 6;
    int dv = rem & 63;
    float4 cv = *(const float4*)(c + ((size_t)(b * CL + i)) * DD + dv * 4);
    float4 g  = *(const float4*)(q2c + b * DD + dv * 4);
    float4 r;
    r.x = cv.x * g.x; r.y = cv.y * g.y; r.z = cv.z * g.z; r.w = cv.w * g.w;
    *(float4*)(out + ((size_t)(b * CL + i)) * (4 * DD) + 3 * DD + dv * 4) = r;
  }
}

extern "C" void kernel_launch(void* const* d_in, const int* in_sizes, int n_in,
                              void* d_out, int out_size, void* d_ws, size_t ws_size,
                              hipStream_t stream) {
  const float* q = (const float*)d_in[0];
  const float* c = (const float*)d_in[1];
  const float* w = (const float*)d_in[2];
  float* out = (float*)d_out;
  char* ws = (char*)d_ws;

  u16*   qbf     = (u16*)(ws);                      // 2,097,152 B
  u16*   qTbf    = (u16*)(ws + 2097152);            // 2,097,152 B
  float* qw      = (float*)(ws + 4194304);          //    16,384 B
  float* rowmax  = (float*)(ws + 4210688);          //   131,072 B
  float* battn   = (float*)(ws + 4341760);          //   131,072 B
  float* partial = (float*)(ws + 4472832);          //   262,144 B
  float* q2c     = (float*)(ws + 4734976);          //     8,192 B

  prep_q_k<<<512, 256, 0, stream>>>(q, w, qbf, qTbf, qw);
  attn_main_k<<<1024, 256, 0, stream>>>(c, w, qbf, qTbf, qw, rowmax, out);
  battn_k<<<8, 256, 0, stream>>>(rowmax, battn);
  q2c_partial_k<<<256, 256, 0, stream>>>(c, battn, partial);
  q2c_final_k<<<8, 256, 0, stream>>>(partial, q2c);
  seg3_k<<<2048, 256, 0, stream>>>(c, q2c, out);
}

// Round 2
// 119.056 us; speedup vs baseline: 1.1223x; 1.1223x over previous
//
#include <hip/hip_runtime.h>

#define BB 8
#define CL 4096
#define QL 512
#define DD 256

typedef unsigned short u16;
typedef float f32x4 __attribute__((ext_vector_type(4)));
typedef short s16x8 __attribute__((ext_vector_type(8)));

static __device__ __forceinline__ u16 f2bf(float x) {
  unsigned int u = __float_as_uint(x);
  u += 0x7FFFu + ((u >> 16) & 1u);
  return (u16)(u >> 16);
}

// ---------------- K0: prep q (bf16 row-major, bf16 transposed, qw dots) ----
// XCD-affine: b = blk & 7 so batch b's q lands in XCD b's L2.
__global__ __launch_bounds__(256) void prep_q_k(
    const float* __restrict__ q, const float* __restrict__ w,
    u16* __restrict__ qbf, u16* __restrict__ qTbf, float* __restrict__ qw_g)
{
  __shared__ u16 qs[8][256];
  __shared__ float red[8][32];
  int blk = blockIdx.x;
  int b = blk & 7;
  int j0 = (blk >> 3) * 8;
  int t = threadIdx.x;
  int r = t >> 5;
  int cs = (t & 31) * 8;

  const float* qrow = q + ((size_t)(b * QL + j0 + r)) * DD + cs;
  float4 v0 = *(const float4*)(qrow);
  float4 v1 = *(const float4*)(qrow + 4);
  float4 w0 = *(const float4*)(w + cs);       // w_q
  float4 w1 = *(const float4*)(w + cs + 4);
  float pw = v0.x*w0.x + v0.y*w0.y + v0.z*w0.z + v0.w*w0.w
           + v1.x*w1.x + v1.y*w1.y + v1.z*w1.z + v1.w*w1.w;

  union { u16 u[8]; uint4 v; } pk;
  pk.u[0]=f2bf(v0.x); pk.u[1]=f2bf(v0.y); pk.u[2]=f2bf(v0.z); pk.u[3]=f2bf(v0.w);
  pk.u[4]=f2bf(v1.x); pk.u[5]=f2bf(v1.y); pk.u[6]=f2bf(v1.z); pk.u[7]=f2bf(v1.w);

  *(uint4*)(qbf + ((size_t)(b * QL + j0 + r)) * DD + cs) = pk.v;
  *(uint4*)(&qs[r][cs]) = pk.v;
  red[r][t & 31] = pw;
  __syncthreads();

  if (t < 8) {
    float s = 0.f;
    #pragma unroll
    for (int k = 0; k < 32; ++k) s += red[t][k];
    qw_g[b * QL + j0 + t] = s;
  }

  int d = t;
  union { u16 u[8]; uint4 v; } tp;
  #pragma unroll
  for (int jj = 0; jj < 8; ++jj) tp.u[jj] = qs[jj][d];
  *(uint4*)(qTbf + ((size_t)(b * DD + d)) * QL + j0) = tp.v;
}

// ---------------- K1: main fused attention over a 32-row c tile -----------
// XCD-affine: b = blk & 7 (q stays L2-resident per XCD).
// LDS 52.3 KB -> 3 blocks/CU. XOR-swizzled cm/P (no pad, conflict-free).
__global__ __launch_bounds__(256, 3) void attn_main_k(
    const float* __restrict__ c, const float* __restrict__ w,
    const u16* __restrict__ qbf, const u16* __restrict__ qTbf,
    const float* __restrict__ qw_g,
    float* __restrict__ pm_g, float* __restrict__ z_g,
    float* __restrict__ part_g, float* __restrict__ out)
{
  __shared__ u16 cm[32 * 256];    // c*w_m bf16, swizzled: idx = r*256 + (d ^ ((r&7)<<3))
  __shared__ u16 P[32 * 512];     // exp(S-m) bf16, swizzled: idx = r*512 + (j ^ ((r&7)<<3))
  __shared__ float qw_s[QL];
  __shared__ float cw_s[32];
  __shared__ float red_m[4][32];
  __shared__ float red_z[4][32];

  int t = threadIdx.x;
  int blk = blockIdx.x;
  int b = blk & 7;
  int tile = blk >> 3;
  int it0 = tile * 32;

  // ---- staging: c tile -> cm bf16 LDS (swizzled), cw dots, seg0 copy ----
  {
    int r = t >> 3;
    int cg = (t & 7) * 32;
    int swz = (r & 7) << 3;
    const float* crow = c + ((size_t)(b * CL + it0 + r)) * DD + cg;
    float* outrow = out + ((size_t)(b * CL + it0 + r)) * (4 * DD) + cg;
    float pcw = 0.f;
    #pragma unroll
    for (int u = 0; u < 32; u += 4) {
      float4 cv  = *(const float4*)(crow + u);
      float4 wcv = *(const float4*)(w + DD + cg + u);      // w_c
      float4 wmv = *(const float4*)(w + 2 * DD + cg + u);  // w_m
      *(float4*)(outrow + u) = cv;                         // segment 0
      pcw += cv.x * wcv.x + cv.y * wcv.y + cv.z * wcv.z + cv.w * wcv.w;
      ushort4 hv;
      hv.x = f2bf(cv.x * wmv.x); hv.y = f2bf(cv.y * wmv.y);
      hv.z = f2bf(cv.z * wmv.z); hv.w = f2bf(cv.w * wmv.w);
      *(ushort4*)(&cm[r * 256 + ((cg + u) ^ swz)]) = hv;
    }
    pcw += __shfl_xor(pcw, 1);
    pcw += __shfl_xor(pcw, 2);
    pcw += __shfl_xor(pcw, 4);
    if ((t & 7) == 0) cw_s[r] = pcw;
    qw_s[t]       = qw_g[b * QL + t];
    qw_s[t + 256] = qw_g[b * QL + 256 + t];
  }
  __syncthreads();

  int wv = t >> 6;       // wave 0..3 -> j chunk of 128
  int ln = t & 63;
  int lr = ln & 15;
  int lg = ln >> 4;
  int jc = wv * 128;
  int aswz = (lr & 7) << 3;   // (16+lr)&7 == lr&7

  // ---- GEMM1: S chunk = cm(32x256) @ q^T, B frags streamed from L2 ----
  f32x4 acc[2][8];
  #pragma unroll
  for (int m = 0; m < 2; ++m)
    #pragma unroll
    for (int n = 0; n < 8; ++n) acc[m][n] = (f32x4){0.f, 0.f, 0.f, 0.f};

  const u16* qb = qbf + (size_t)b * QL * DD;
  #pragma unroll
  for (int k = 0; k < 8; ++k) {
    s16x8 a0 = *(const s16x8*)(&cm[lr * 256 + ((k * 32 + lg * 8) ^ aswz)]);
    s16x8 a1 = *(const s16x8*)(&cm[(16 + lr) * 256 + ((k * 32 + lg * 8) ^ aswz)]);
    #pragma unroll
    for (int n = 0; n < 8; ++n) {
      s16x8 bq = *(const s16x8*)(qb + ((size_t)(jc + n * 16 + lr)) * DD + k * 32 + lg * 8);
      acc[0][n] = __builtin_amdgcn_mfma_f32_16x16x32_bf16(a0, bq, acc[0][n], 0, 0, 0);
      acc[1][n] = __builtin_amdgcn_mfma_f32_16x16x32_bf16(a1, bq, acc[1][n], 0, 0, 0);
    }
  }

  // ---- softmax from registers (C/D layout: col=lr, row=lg*4+rr) ----
  float qwv[8];
  #pragma unroll
  for (int n = 0; n < 8; ++n) qwv[n] = qw_s[jc + n * 16 + lr];

  float mrow[2][4], invz[2][4];
  #pragma unroll
  for (int m = 0; m < 2; ++m) {
    #pragma unroll
    for (int rr = 0; rr < 4; ++rr) {
      int row = m * 16 + lg * 4 + rr;
      float cwv = cw_s[row];
      float mx = -1e30f;
      #pragma unroll
      for (int n = 0; n < 8; ++n) {
        float s = acc[m][n][rr] + cwv + qwv[n];
        acc[m][n][rr] = s;
        mx = fmaxf(mx, s);
      }
      mx = fmaxf(mx, __shfl_xor(mx, 1));
      mx = fmaxf(mx, __shfl_xor(mx, 2));
      mx = fmaxf(mx, __shfl_xor(mx, 4));
      mx = fmaxf(mx, __shfl_xor(mx, 8));
      if (lr == 0) red_m[wv][row] = mx;
    }
  }
  __syncthreads();
  #pragma unroll
  for (int m = 0; m < 2; ++m) {
    #pragma unroll
    for (int rr = 0; rr < 4; ++rr) {
      int row = m * 16 + lg * 4 + rr;
      float mr = fmaxf(fmaxf(red_m[0][row], red_m[1][row]),
                       fmaxf(red_m[2][row], red_m[3][row]));
      mrow[m][rr] = mr;
      float s = 0.f;
      #pragma unroll
      for (int n = 0; n < 8; ++n) {
        float e = __expf(acc[m][n][rr] - mr);
        acc[m][n][rr] = e;
        s += e;
      }
      s += __shfl_xor(s, 1);
      s += __shfl_xor(s, 2);
      s += __shfl_xor(s, 4);
      s += __shfl_xor(s, 8);
      if (lr == 0) red_z[wv][row] = s;
    }
  }
  __syncthreads();
  // P stores raw exp (unnormalized); invz applied in epilogue.
  #pragma unroll
  for (int m = 0; m < 2; ++m) {
    #pragma unroll
    for (int rr = 0; rr < 4; ++rr) {
      int row = m * 16 + lg * 4 + rr;
      float z = red_z[0][row] + red_z[1][row] + red_z[2][row] + red_z[3][row];
      invz[m][rr] = 1.0f / z;
      int pswz = (row & 7) << 3;
      #pragma unroll
      for (int n = 0; n < 8; ++n)
        P[row * 512 + ((jc + n * 16 + lr) ^ pswz)] = f2bf(acc[m][n][rr]);
    }
  }
  __syncthreads();

  // ---- GEMM2: c2q = P(32x512) @ q(512x256); waves split d in 64s ----
  f32x4 o2[2][4];
  #pragma unroll
  for (int m = 0; m < 2; ++m)
    #pragma unroll
    for (int n = 0; n < 4; ++n) o2[m][n] = (f32x4){0.f, 0.f, 0.f, 0.f};

  const u16* qtb = qTbf + (size_t)b * DD * QL;
  #pragma unroll 4
  for (int k = 0; k < 16; ++k) {
    s16x8 a0 = *(const s16x8*)(&P[lr * 512 + ((k * 32 + lg * 8) ^ aswz)]);
    s16x8 a1 = *(const s16x8*)(&P[(16 + lr) * 512 + ((k * 32 + lg * 8) ^ aswz)]);
    #pragma unroll
    for (int n = 0; n < 4; ++n) {
      s16x8 bv = *(const s16x8*)(qtb + ((size_t)(wv * 64 + n * 16 + lr)) * QL + k * 32 + lg * 8);
      o2[0][n] = __builtin_amdgcn_mfma_f32_16x16x32_bf16(a0, bv, o2[0][n], 0, 0, 0);
      o2[1][n] = __builtin_amdgcn_mfma_f32_16x16x32_bf16(a1, bv, o2[1][n], 0, 0, 0);
    }
  }

  // ---- block stats for q2c (local-max log-sum-exp tile partials) ----
  float pmx = -1e30f;
  #pragma unroll
  for (int m = 0; m < 2; ++m)
    #pragma unroll
    for (int rr = 0; rr < 4; ++rr) pmx = fmaxf(pmx, mrow[m][rr]);
  pmx = fmaxf(pmx, __shfl_xor(pmx, 16));
  pmx = fmaxf(pmx, __shfl_xor(pmx, 32));
  float zs = 0.f;
  float wgt[2][4];
  #pragma unroll
  for (int m = 0; m < 2; ++m)
    #pragma unroll
    for (int rr = 0; rr < 4; ++rr) {
      wgt[m][rr] = __expf(mrow[m][rr] - pmx);
      zs += wgt[m][rr];
    }
  zs += __shfl_xor(zs, 16);
  zs += __shfl_xor(zs, 32);
  if (t == 0) { pm_g[b * 128 + tile] = pmx; z_g[b * 128 + tile] = zs; }

  // ---- epilogue: segments 1 (c2q), 2 (c*c2q), q2c partial ----
  #pragma unroll
  for (int n = 0; n < 4; ++n) {
    int dcol = wv * 64 + n * 16 + lr;
    float psum = 0.f;
    #pragma unroll
    for (int m = 0; m < 2; ++m)
      #pragma unroll
      for (int rr = 0; rr < 4; ++rr) {
        int row = it0 + m * 16 + lg * 4 + rr;
        float c2q = o2[m][n][rr] * invz[m][rr];
        float cv = c[((size_t)(b * CL + row)) * DD + dcol];
        size_t ob = ((size_t)(b * CL + row)) * (4 * DD);
        out[ob + DD + dcol] = c2q;
        out[ob + 2 * DD + dcol] = cv * c2q;
        psum += wgt[m][rr] * cv;
      }
    psum += __shfl_xor(psum, 16);
    psum += __shfl_xor(psum, 32);
    if (ln < 16) part_g[((size_t)(b * 128 + tile)) * DD + dcol] = psum;
  }
}

// ---------------- K2: combine tile partials -> q2c ------------------------
__global__ __launch_bounds__(256) void q2c_reduce_k(
    const float* __restrict__ pm_g, const float* __restrict__ z_g,
    const float* __restrict__ part_g, float* __restrict__ q2c)
{
  __shared__ float wk[128];
  __shared__ float rm[4];
  __shared__ float rz[4];
  int b = blockIdx.x;
  int t = threadIdx.x;

  float p = (t < 128) ? pm_g[b * 128 + t] : -1e30f;
  float m = p;
  #pragma unroll
  for (int o = 1; o < 64; o <<= 1) m = fmaxf(m, __shfl_xor(m, o));
  if ((t & 63) == 0) rm[t >> 6] = m;
  __syncthreads();
  float M = fmaxf(fmaxf(rm[0], rm[1]), fmaxf(rm[2], rm[3]));

  float ew = (t < 128) ? __expf(p - M) : 0.f;
  float zi = (t < 128) ? ew * z_g[b * 128 + t] : 0.f;
  float s = zi;
  #pragma unroll
  for (int o = 1; o < 64; o <<= 1) s += __shfl_xor(s, o);
  if ((t & 63) == 0) rz[t >> 6] = s;
  __syncthreads();
  float Z = rz[0] + rz[1] + rz[2] + rz[3];

  if (t < 128) wk[t] = ew / Z;
  __syncthreads();

  float acc = 0.f;
  for (int k = 0; k < 128; ++k)
    acc += wk[k] * part_g[((size_t)(b * 128 + k)) * DD + t];
  q2c[b * DD + t] = acc;
}

// ---------------- K3: out segment 3 = c * q2c -----------------------------
__global__ __launch_bounds__(256) void seg3_k(
    const float* __restrict__ c, const float* __restrict__ q2c,
    float* __restrict__ out)
{
  size_t stride = (size_t)gridDim.x * 256;
  size_t total = (size_t)BB * CL * (DD / 4);  // float4 count
  for (size_t e = (size_t)blockIdx.x * 256 + threadIdx.x; e < total; e += stride) {
    int b = (int)(e >> 18);
    int rem = (int)(e & 262143);
    int i = rem >> 6;
    int dv = rem & 63;
    float4 cv = *(const float4*)(c + ((size_t)(b * CL + i)) * DD + dv * 4);
    float4 g  = *(const float4*)(q2c + b * DD + dv * 4);
    float4 r;
    r.x = cv.x * g.x; r.y = cv.y * g.y; r.z = cv.z * g.z; r.w = cv.w * g.w;
    *(float4*)(out + ((size_t)(b * CL + i)) * (4 * DD) + 3 * DD + dv * 4) = r;
  }
}

extern "C" void kernel_launch(void* const* d_in, const int* in_sizes, int n_in,
                              void* d_out, int out_size, void* d_ws, size_t ws_size,
                              hipStream_t stream) {
  const float* q = (const float*)d_in[0];
  const float* c = (const float*)d_in[1];
  const float* w = (const float*)d_in[2];
  float* out = (float*)d_out;
  char* ws = (char*)d_ws;

  u16*   qbf   = (u16*)(ws);                    // 2,097,152 B
  u16*   qTbf  = (u16*)(ws + 2097152);          // 2,097,152 B
  float* qw    = (float*)(ws + 4194304);        //    16,384 B
  float* pm    = (float*)(ws + 4210688);        //     4,096 B
  float* zb    = (float*)(ws + 4214784);        //     4,096 B
  float* part  = (float*)(ws + 4218880);        // 1,048,576 B
  float* q2c   = (float*)(ws + 5267456);        //     8,192 B

  prep_q_k<<<512, 256, 0, stream>>>(q, w, qbf, qTbf, qw);
  attn_main_k<<<1024, 256, 0, stream>>>(c, w, qbf, qTbf, qw, pm, zb, part, out);
  q2c_reduce_k<<<8, 256, 0, stream>>>(pm, zb, part, q2c);
  seg3_k<<<2048, 256, 0, stream>>>(c, q2c, out);
}

// Round 3
// 111.942 us; speedup vs baseline: 1.1936x; 1.0635x over previous
//
#include <hip/hip_runtime.h>

#define BB 8
#define CL 4096
#define QL 512
#define DD 256

typedef unsigned short u16;
typedef float f32x4 __attribute__((ext_vector_type(4)));
typedef short s16x8 __attribute__((ext_vector_type(8)));

static __device__ __forceinline__ u16 f2bf(float x) {
  unsigned int u = __float_as_uint(x);
  u += 0x7FFFu + ((u >> 16) & 1u);
  return (u16)(u >> 16);
}

// ---------------- K0: prep q (bf16 row-major, bf16 transposed, qw dots) ----
// XCD-affine: b = blk & 7 so batch b's q lands in XCD b's L2.
__global__ __launch_bounds__(256) void prep_q_k(
    const float* __restrict__ q, const float* __restrict__ w,
    u16* __restrict__ qbf, u16* __restrict__ qTbf, float* __restrict__ qw_g)
{
  __shared__ u16 qs[8][256];
  __shared__ float red[8][32];
  int blk = blockIdx.x;
  int b = blk & 7;
  int j0 = (blk >> 3) * 8;
  int t = threadIdx.x;
  int r = t >> 5;
  int cs = (t & 31) * 8;

  const float* qrow = q + ((size_t)(b * QL + j0 + r)) * DD + cs;
  float4 v0 = *(const float4*)(qrow);
  float4 v1 = *(const float4*)(qrow + 4);
  float4 w0 = *(const float4*)(w + cs);       // w_q
  float4 w1 = *(const float4*)(w + cs + 4);
  float pw = v0.x*w0.x + v0.y*w0.y + v0.z*w0.z + v0.w*w0.w
           + v1.x*w1.x + v1.y*w1.y + v1.z*w1.z + v1.w*w1.w;

  union { u16 u[8]; uint4 v; } pk;
  pk.u[0]=f2bf(v0.x); pk.u[1]=f2bf(v0.y); pk.u[2]=f2bf(v0.z); pk.u[3]=f2bf(v0.w);
  pk.u[4]=f2bf(v1.x); pk.u[5]=f2bf(v1.y); pk.u[6]=f2bf(v1.z); pk.u[7]=f2bf(v1.w);

  *(uint4*)(qbf + ((size_t)(b * QL + j0 + r)) * DD + cs) = pk.v;
  *(uint4*)(&qs[r][cs]) = pk.v;
  red[r][t & 31] = pw;
  __syncthreads();

  if (t < 8) {
    float s = 0.f;
    #pragma unroll
    for (int k = 0; k < 32; ++k) s += red[t][k];
    qw_g[b * QL + j0 + t] = s;
  }

  int d = t;
  union { u16 u[8]; uint4 v; } tp;
  #pragma unroll
  for (int jj = 0; jj < 8; ++jj) tp.u[jj] = qs[jj][d];
  *(uint4*)(qTbf + ((size_t)(b * DD + d)) * QL + j0) = tp.v;
}

// ---------------- K1: main fused attention over a 32-row c tile -----------
// XCD-affine: b = blk & 7. LDS: cm and P ALIAS one 32 KB pool (cm dead after
// GEMM1; P written only after the post-GEMM1 barrier) -> 35.9 KB -> 4 blk/CU.
__global__ __launch_bounds__(256, 4) void attn_main_k(
    const float* __restrict__ c, const float* __restrict__ w,
    const u16* __restrict__ qbf, const u16* __restrict__ qTbf,
    const float* __restrict__ qw_g,
    float* __restrict__ pm_g, float* __restrict__ z_g,
    float* __restrict__ part_g, float* __restrict__ out)
{
  __shared__ u16 pool[32 * 512];  // cm: [r*256 + (d ^ swz)] ; P: [r*512 + (j ^ swz)]
  __shared__ float qw_s[QL];
  __shared__ float cw_s[32];
  __shared__ float red_m[4][32];
  __shared__ float red_z[4][32];

  int t = threadIdx.x;
  int blk = blockIdx.x;
  int b = blk & 7;
  int tile = blk >> 3;
  int it0 = tile * 32;

  // ---- staging: c tile -> cm bf16 LDS (swizzled), cw dots, seg0 copy ----
  {
    int r = t >> 3;
    int cg = (t & 7) * 32;
    int swz = (r & 7) << 3;
    const float* crow = c + ((size_t)(b * CL + it0 + r)) * DD + cg;
    float* outrow = out + ((size_t)(b * CL + it0 + r)) * (4 * DD) + cg;
    float pcw = 0.f;
    #pragma unroll
    for (int u = 0; u < 32; u += 4) {
      float4 cv  = *(const float4*)(crow + u);
      float4 wcv = *(const float4*)(w + DD + cg + u);      // w_c
      float4 wmv = *(const float4*)(w + 2 * DD + cg + u);  // w_m
      *(float4*)(outrow + u) = cv;                         // segment 0
      pcw += cv.x * wcv.x + cv.y * wcv.y + cv.z * wcv.z + cv.w * wcv.w;
      ushort4 hv;
      hv.x = f2bf(cv.x * wmv.x); hv.y = f2bf(cv.y * wmv.y);
      hv.z = f2bf(cv.z * wmv.z); hv.w = f2bf(cv.w * wmv.w);
      *(ushort4*)(&pool[r * 256 + ((cg + u) ^ swz)]) = hv;
    }
    pcw += __shfl_xor(pcw, 1);
    pcw += __shfl_xor(pcw, 2);
    pcw += __shfl_xor(pcw, 4);
    if ((t & 7) == 0) cw_s[r] = pcw;
    qw_s[t]       = qw_g[b * QL + t];
    qw_s[t + 256] = qw_g[b * QL + 256 + t];
  }
  __syncthreads();

  int wv = t >> 6;       // wave 0..3 -> j chunk of 128
  int ln = t & 63;
  int lr = ln & 15;
  int lg = ln >> 4;
  int jc = wv * 128;
  int aswz = (lr & 7) << 3;

  // ---- GEMM1: S chunk = cm(32x256) @ q^T, B frags streamed from L2 ----
  f32x4 acc[2][8];
  #pragma unroll
  for (int m = 0; m < 2; ++m)
    #pragma unroll
    for (int n = 0; n < 8; ++n) acc[m][n] = (f32x4){0.f, 0.f, 0.f, 0.f};

  const u16* qb = qbf + (size_t)b * QL * DD + (size_t)(jc + lr) * DD;
  #pragma unroll
  for (int k = 0; k < 8; ++k) {
    s16x8 a0 = *(const s16x8*)(&pool[lr * 256 + ((k * 32 + lg * 8) ^ aswz)]);
    s16x8 a1 = *(const s16x8*)(&pool[(16 + lr) * 256 + ((k * 32 + lg * 8) ^ aswz)]);
    #pragma unroll
    for (int h = 0; h < 2; ++h) {
      s16x8 bq[4];
      #pragma unroll
      for (int n4 = 0; n4 < 4; ++n4)
        bq[n4] = *(const s16x8*)(qb + ((size_t)((h * 4 + n4) * 16)) * DD + k * 32 + lg * 8);
      #pragma unroll
      for (int n4 = 0; n4 < 4; ++n4) {
        acc[0][h * 4 + n4] = __builtin_amdgcn_mfma_f32_16x16x32_bf16(a0, bq[n4], acc[0][h * 4 + n4], 0, 0, 0);
        acc[1][h * 4 + n4] = __builtin_amdgcn_mfma_f32_16x16x32_bf16(a1, bq[n4], acc[1][h * 4 + n4], 0, 0, 0);
      }
    }
  }

  // ---- softmax pass 1: bias + row max (C/D: col=lr, row=lg*4+rr) ----
  float qwv[8];
  #pragma unroll
  for (int n = 0; n < 8; ++n) qwv[n] = qw_s[jc + n * 16 + lr];

  float mrow[2][4], invz[2][4];
  #pragma unroll
  for (int m = 0; m < 2; ++m) {
    #pragma unroll
    for (int rr = 0; rr < 4; ++rr) {
      int row = m * 16 + lg * 4 + rr;
      float cwv = cw_s[row];
      float mx = -1e30f;
      #pragma unroll
      for (int n = 0; n < 8; ++n) {
        float s = acc[m][n][rr] + cwv + qwv[n];
        acc[m][n][rr] = s;
        mx = fmaxf(mx, s);
      }
      mx = fmaxf(mx, __shfl_xor(mx, 1));
      mx = fmaxf(mx, __shfl_xor(mx, 2));
      mx = fmaxf(mx, __shfl_xor(mx, 4));
      mx = fmaxf(mx, __shfl_xor(mx, 8));
      if (lr == 0) red_m[wv][row] = mx;
    }
  }
  __syncthreads();   // red_m visible; all cm reads done -> pool reusable as P

  // ---- softmax pass 2: exp, write raw-exp P (swizzled), z partials ----
  #pragma unroll
  for (int m = 0; m < 2; ++m) {
    #pragma unroll
    for (int rr = 0; rr < 4; ++rr) {
      int row = m * 16 + lg * 4 + rr;
      float mr = fmaxf(fmaxf(red_m[0][row], red_m[1][row]),
                       fmaxf(red_m[2][row], red_m[3][row]));
      mrow[m][rr] = mr;
      int pswz = (row & 7) << 3;
      float s = 0.f;
      #pragma unroll
      for (int n = 0; n < 8; ++n) {
        float e = __expf(acc[m][n][rr] - mr);
        pool[row * 512 + ((jc + n * 16 + lr) ^ pswz)] = f2bf(e);
        s += e;
      }
      s += __shfl_xor(s, 1);
      s += __shfl_xor(s, 2);
      s += __shfl_xor(s, 4);
      s += __shfl_xor(s, 8);
      if (lr == 0) red_z[wv][row] = s;
    }
  }
  __syncthreads();   // P + red_z visible

  // ---- GEMM2: c2q = P(32x512) @ q(512x256); waves split d in 64s ----
  f32x4 o2[2][4];
  #pragma unroll
  for (int m = 0; m < 2; ++m)
    #pragma unroll
    for (int n = 0; n < 4; ++n) o2[m][n] = (f32x4){0.f, 0.f, 0.f, 0.f};

  const u16* qtb = qTbf + (size_t)b * DD * QL + (size_t)(wv * 64 + lr) * QL;
  #pragma unroll 4
  for (int k = 0; k < 16; ++k) {
    s16x8 a0 = *(const s16x8*)(&pool[lr * 512 + ((k * 32 + lg * 8) ^ aswz)]);
    s16x8 a1 = *(const s16x8*)(&pool[(16 + lr) * 512 + ((k * 32 + lg * 8) ^ aswz)]);
    s16x8 bv[4];
    #pragma unroll
    for (int n = 0; n < 4; ++n)
      bv[n] = *(const s16x8*)(qtb + ((size_t)(n * 16)) * QL + k * 32 + lg * 8);
    #pragma unroll
    for (int n = 0; n < 4; ++n) {
      o2[0][n] = __builtin_amdgcn_mfma_f32_16x16x32_bf16(a0, bv[n], o2[0][n], 0, 0, 0);
      o2[1][n] = __builtin_amdgcn_mfma_f32_16x16x32_bf16(a1, bv[n], o2[1][n], 0, 0, 0);
    }
  }

  // ---- finalize z, block stats for q2c ----
  #pragma unroll
  for (int m = 0; m < 2; ++m)
    #pragma unroll
    for (int rr = 0; rr < 4; ++rr) {
      int row = m * 16 + lg * 4 + rr;
      invz[m][rr] = 1.0f / (red_z[0][row] + red_z[1][row] + red_z[2][row] + red_z[3][row]);
    }

  float pmx = -1e30f;
  #pragma unroll
  for (int m = 0; m < 2; ++m)
    #pragma unroll
    for (int rr = 0; rr < 4; ++rr) pmx = fmaxf(pmx, mrow[m][rr]);
  pmx = fmaxf(pmx, __shfl_xor(pmx, 16));
  pmx = fmaxf(pmx, __shfl_xor(pmx, 32));
  float zs = 0.f;
  float wgt[2][4];
  #pragma unroll
  for (int m = 0; m < 2; ++m)
    #pragma unroll
    for (int rr = 0; rr < 4; ++rr) {
      wgt[m][rr] = __expf(mrow[m][rr] - pmx);
      zs += wgt[m][rr];
    }
  zs += __shfl_xor(zs, 16);
  zs += __shfl_xor(zs, 32);
  if (t == 0) { pm_g[b * 128 + tile] = pmx; z_g[b * 128 + tile] = zs; }

  // ---- epilogue: segments 1 (c2q), 2 (c*c2q), q2c partial ----
  #pragma unroll
  for (int n = 0; n < 4; ++n) {
    int dcol = wv * 64 + n * 16 + lr;
    float psum = 0.f;
    #pragma unroll
    for (int m = 0; m < 2; ++m)
      #pragma unroll
      for (int rr = 0; rr < 4; ++rr) {
        int row = it0 + m * 16 + lg * 4 + rr;
        float c2q = o2[m][n][rr] * invz[m][rr];
        float cv = c[((size_t)(b * CL + row)) * DD + dcol];
        size_t ob = ((size_t)(b * CL + row)) * (4 * DD);
        out[ob + DD + dcol] = c2q;
        out[ob + 2 * DD + dcol] = cv * c2q;
        psum += wgt[m][rr] * cv;
      }
    psum += __shfl_xor(psum, 16);
    psum += __shfl_xor(psum, 32);
    if (ln < 16) part_g[((size_t)(b * 128 + tile)) * DD + dcol] = psum;
  }
}

// ---------------- K2: combine tile partials -> q2c ------------------------
__global__ __launch_bounds__(256) void q2c_reduce_k(
    const float* __restrict__ pm_g, const float* __restrict__ z_g,
    const float* __restrict__ part_g, float* __restrict__ q2c)
{
  __shared__ float wk[128];
  __shared__ float rm[4];
  __shared__ float rz[4];
  int b = blockIdx.x;
  int t = threadIdx.x;

  float p = (t < 128) ? pm_g[b * 128 + t] : -1e30f;
  float m = p;
  #pragma unroll
  for (int o = 1; o < 64; o <<= 1) m = fmaxf(m, __shfl_xor(m, o));
  if ((t & 63) == 0) rm[t >> 6] = m;
  __syncthreads();
  float M = fmaxf(fmaxf(rm[0], rm[1]), fmaxf(rm[2], rm[3]));

  float ew = (t < 128) ? __expf(p - M) : 0.f;
  float zi = (t < 128) ? ew * z_g[b * 128 + t] : 0.f;
  float s = zi;
  #pragma unroll
  for (int o = 1; o < 64; o <<= 1) s += __shfl_xor(s, o);
  if ((t & 63) == 0) rz[t >> 6] = s;
  __syncthreads();
  float Z = rz[0] + rz[1] + rz[2] + rz[3];

  if (t < 128) wk[t] = ew / Z;
  __syncthreads();

  float acc = 0.f;
  for (int k = 0; k < 128; ++k)
    acc += wk[k] * part_g[((size_t)(b * 128 + k)) * DD + t];
  q2c[b * DD + t] = acc;
}

// ---------------- K3: out segment 3 = c * q2c -----------------------------
__global__ __launch_bounds__(256) void seg3_k(
    const float* __restrict__ c, const float* __restrict__ q2c,
    float* __restrict__ out)
{
  size_t stride = (size_t)gridDim.x * 256;
  size_t total = (size_t)BB * CL * (DD / 4);  // float4 count
  for (size_t e = (size_t)blockIdx.x * 256 + threadIdx.x; e < total; e += stride) {
    int b = (int)(e >> 18);
    int rem = (int)(e & 262143);
    int i = rem >> 6;
    int dv = rem & 63;
    float4 cv = *(const float4*)(c + ((size_t)(b * CL + i)) * DD + dv * 4);
    float4 g  = *(const float4*)(q2c + b * DD + dv * 4);
    float4 r;
    r.x = cv.x * g.x; r.y = cv.y * g.y; r.z = cv.z * g.z; r.w = cv.w * g.w;
    *(float4*)(out + ((size_t)(b * CL + i)) * (4 * DD) + 3 * DD + dv * 4) = r;
  }
}

extern "C" void kernel_launch(void* const* d_in, const int* in_sizes, int n_in,
                              void* d_out, int out_size, void* d_ws, size_t ws_size,
                              hipStream_t stream) {
  const float* q = (const float*)d_in[0];
  const float* c = (const float*)d_in[1];
  const float* w = (const float*)d_in[2];
  float* out = (float*)d_out;
  char* ws = (char*)d_ws;

  u16*   qbf   = (u16*)(ws);                    // 2,097,152 B
  u16*   qTbf  = (u16*)(ws + 2097152);          // 2,097,152 B
  float* qw    = (float*)(ws + 4194304);        //    16,384 B
  float* pm    = (float*)(ws + 4210688);        //     4,096 B
  float* zb    = (float*)(ws + 4214784);        //     4,096 B
  float* part  = (float*)(ws + 4218880);        // 1,048,576 B
  float* q2c   = (float*)(ws + 5267456);        //     8,192 B

  prep_q_k<<<512, 256, 0, stream>>>(q, w, qbf, qTbf, qw);
  attn_main_k<<<1024, 256, 0, stream>>>(c, w, qbf, qTbf, qw, pm, zb, part, out);
  q2c_reduce_k<<<8, 256, 0, stream>>>(pm, zb, part, q2c);
  seg3_k<<<2048, 256, 0, stream>>>(c, q2c, out);
}

// Round 4
// 89.746 us; speedup vs baseline: 1.4888x; 1.2473x over previous
//
#include <hip/hip_runtime.h>

#define BB 8
#define CL 4096
#define QL 512
#define DD 256

typedef unsigned short u16;
typedef float f32x4 __attribute__((ext_vector_type(4)));
typedef short s16x8 __attribute__((ext_vector_type(8)));

static __device__ __forceinline__ u16 f2bf(float x) {
  unsigned int u = __float_as_uint(x);
  u += 0x7FFFu + ((u >> 16) & 1u);
  return (u16)(u >> 16);
}

// ---------------- K0: prep q (bf16 row-major, bf16 transposed, qw dots) ----
__global__ __launch_bounds__(256) void prep_q_k(
    const float* __restrict__ q, const float* __restrict__ w,
    u16* __restrict__ qbf, u16* __restrict__ qTbf, float* __restrict__ qw_g)
{
  __shared__ u16 qs[8][256];
  __shared__ float red[8][32];
  int blk = blockIdx.x;
  int b = blk & 7;
  int j0 = (blk >> 3) * 8;
  int t = threadIdx.x;
  int r = t >> 5;
  int cs = (t & 31) * 8;

  const float* qrow = q + ((size_t)(b * QL + j0 + r)) * DD + cs;
  float4 v0 = *(const float4*)(qrow);
  float4 v1 = *(const float4*)(qrow + 4);
  float4 w0 = *(const float4*)(w + cs);       // w_q
  float4 w1 = *(const float4*)(w + cs + 4);
  float pw = v0.x*w0.x + v0.y*w0.y + v0.z*w0.z + v0.w*w0.w
           + v1.x*w1.x + v1.y*w1.y + v1.z*w1.z + v1.w*w1.w;

  union { u16 u[8]; uint4 v; } pk;
  pk.u[0]=f2bf(v0.x); pk.u[1]=f2bf(v0.y); pk.u[2]=f2bf(v0.z); pk.u[3]=f2bf(v0.w);
  pk.u[4]=f2bf(v1.x); pk.u[5]=f2bf(v1.y); pk.u[6]=f2bf(v1.z); pk.u[7]=f2bf(v1.w);

  *(uint4*)(qbf + ((size_t)(b * QL + j0 + r)) * DD + cs) = pk.v;
  *(uint4*)(&qs[r][cs]) = pk.v;
  red[r][t & 31] = pw;
  __syncthreads();

  if (t < 8) {
    float s = 0.f;
    #pragma unroll
    for (int k = 0; k < 32; ++k) s += red[t][k];
    qw_g[b * QL + j0 + t] = s;
  }

  int d = t;
  union { u16 u[8]; uint4 v; } tp;
  #pragma unroll
  for (int jj = 0; jj < 8; ++jj) tp.u[jj] = qs[jj][d];
  *(uint4*)(qTbf + ((size_t)(b * DD + d)) * QL + j0) = tp.v;
}

// ---------------- K1: 64-row c tile, 8 waves, 2 blocks/CU -----------------
__global__ __launch_bounds__(512, 4) void attn_main_k(
    const float* __restrict__ c, const float* __restrict__ w,
    const u16* __restrict__ qbf, const u16* __restrict__ qTbf,
    const float* __restrict__ qw_g,
    float* __restrict__ pm_g, float* __restrict__ z_g,
    float* __restrict__ part_g, float* __restrict__ out)
{
  __shared__ u16 pool[64 * 512];     // cm: [r*256+(d^swz)] (32KB); P: [r*512+(j^swz)] (64KB)
  __shared__ float qw_s[QL];
  __shared__ float cw_s[64];
  __shared__ float red_m[64][8];     // [row][wave]
  __shared__ float red_z[64][8];
  __shared__ float invz_s[64];
  __shared__ float wgt_s[64];

  int t = threadIdx.x;
  int blk = blockIdx.x;
  int b = blk & 7;
  int tile = blk >> 3;
  int it0 = tile * 64;

  // ---- staging: c tile -> cm bf16 LDS (swizzled), cw dots, seg0 copy ----
  {
    int r = t >> 3;
    int cg = (t & 7) * 32;
    int swz = (r & 7) << 3;
    const float* crow = c + ((size_t)(b * CL + it0 + r)) * DD + cg;
    float* outrow = out + ((size_t)(b * CL + it0 + r)) * (4 * DD) + cg;
    float pcw = 0.f;
    #pragma unroll
    for (int u = 0; u < 32; u += 4) {
      float4 cv  = *(const float4*)(crow + u);
      float4 wcv = *(const float4*)(w + DD + cg + u);      // w_c
      float4 wmv = *(const float4*)(w + 2 * DD + cg + u);  // w_m
      *(float4*)(outrow + u) = cv;                         // segment 0
      pcw += cv.x * wcv.x + cv.y * wcv.y + cv.z * wcv.z + cv.w * wcv.w;
      ushort4 hv;
      hv.x = f2bf(cv.x * wmv.x); hv.y = f2bf(cv.y * wmv.y);
      hv.z = f2bf(cv.z * wmv.z); hv.w = f2bf(cv.w * wmv.w);
      *(ushort4*)(&pool[r * 256 + ((cg + u) ^ swz)]) = hv;
    }
    pcw += __shfl_xor(pcw, 1);
    pcw += __shfl_xor(pcw, 2);
    pcw += __shfl_xor(pcw, 4);
    if ((t & 7) == 0) cw_s[r] = pcw;
    qw_s[t] = qw_g[b * QL + t];
  }
  __syncthreads();

  int wv = t >> 6;       // wave 0..7
  int ln = t & 63;
  int lr = ln & 15;
  int lg = ln >> 4;
  int jc = wv * 64;      // GEMM1 j-chunk
  int aswz = (lr & 7) << 3;

  // ---- GEMM1: S chunk = cm(64x256) @ q^T; B frags from L2, k+1 prefetch --
  f32x4 acc[4][4];
  #pragma unroll
  for (int m = 0; m < 4; ++m)
    #pragma unroll
    for (int n = 0; n < 4; ++n) acc[m][n] = (f32x4){0.f, 0.f, 0.f, 0.f};

  const u16* qb = qbf + (size_t)b * QL * DD + (size_t)(jc + lr) * DD + lg * 8;
  s16x8 bqn[4];
  #pragma unroll
  for (int n = 0; n < 4; ++n) bqn[n] = *(const s16x8*)(qb + (size_t)(n * 16) * DD);
  #pragma unroll
  for (int kk = 0; kk < 8; ++kk) {
    s16x8 bqc[4];
    #pragma unroll
    for (int n = 0; n < 4; ++n) bqc[n] = bqn[n];
    if (kk < 7) {
      #pragma unroll
      for (int n = 0; n < 4; ++n)
        bqn[n] = *(const s16x8*)(qb + (size_t)(n * 16) * DD + (kk + 1) * 32);
    }
    s16x8 a[4];
    #pragma unroll
    for (int m = 0; m < 4; ++m)
      a[m] = *(const s16x8*)(&pool[(m * 16 + lr) * 256 + ((kk * 32 + lg * 8) ^ aswz)]);
    #pragma unroll
    for (int m = 0; m < 4; ++m)
      #pragma unroll
      for (int n = 0; n < 4; ++n)
        acc[m][n] = __builtin_amdgcn_mfma_f32_16x16x32_bf16(a[m], bqc[n], acc[m][n], 0, 0, 0);
  }

  // ---- softmax pass 1: bias + row max (D: col=lr->j, row=lg*4+rr->i) ----
  float qwv[4];
  #pragma unroll
  for (int n = 0; n < 4; ++n) qwv[n] = qw_s[jc + n * 16 + lr];

  #pragma unroll
  for (int m = 0; m < 4; ++m) {
    #pragma unroll
    for (int rr = 0; rr < 4; ++rr) {
      int row = m * 16 + lg * 4 + rr;
      float cwv = cw_s[row];
      float mx = -1e30f;
      #pragma unroll
      for (int n = 0; n < 4; ++n) {
        float s = acc[m][n][rr] + cwv + qwv[n];
        acc[m][n][rr] = s;
        mx = fmaxf(mx, s);
      }
      mx = fmaxf(mx, __shfl_xor(mx, 1));
      mx = fmaxf(mx, __shfl_xor(mx, 2));
      mx = fmaxf(mx, __shfl_xor(mx, 4));
      mx = fmaxf(mx, __shfl_xor(mx, 8));
      if (lr == 0) red_m[row][wv] = mx;
    }
  }
  __syncthreads();   // red_m visible; cm reads done -> pool reusable as P

  // ---- softmax pass 2: exp, write raw-exp P (swizzled), z partials ----
  #pragma unroll
  for (int m = 0; m < 4; ++m) {
    #pragma unroll
    for (int rr = 0; rr < 4; ++rr) {
      int row = m * 16 + lg * 4 + rr;
      float4 m0 = *(const float4*)(&red_m[row][0]);
      float4 m1 = *(const float4*)(&red_m[row][4]);
      float mr = fmaxf(fmaxf(fmaxf(m0.x, m0.y), fmaxf(m0.z, m0.w)),
                       fmaxf(fmaxf(m1.x, m1.y), fmaxf(m1.z, m1.w)));
      int pswz = (row & 7) << 3;
      float s = 0.f;
      #pragma unroll
      for (int n = 0; n < 4; ++n) {
        float e = __expf(acc[m][n][rr] - mr);
        pool[row * 512 + ((jc + n * 16 + lr) ^ pswz)] = f2bf(e);
        s += e;
      }
      s += __shfl_xor(s, 1);
      s += __shfl_xor(s, 2);
      s += __shfl_xor(s, 4);
      s += __shfl_xor(s, 8);
      if (lr == 0) red_z[row][wv] = s;
    }
  }
  __syncthreads();   // P + red_z visible

  // ---- wave 0: per-row invz/wgt into LDS; pm/z stats to global ----
  if (wv == 0) {
    int row = ln;  // 64 lanes -> 64 rows
    float4 m0 = *(const float4*)(&red_m[row][0]);
    float4 m1 = *(const float4*)(&red_m[row][4]);
    float mr = fmaxf(fmaxf(fmaxf(m0.x, m0.y), fmaxf(m0.z, m0.w)),
                     fmaxf(fmaxf(m1.x, m1.y), fmaxf(m1.z, m1.w)));
    float4 z0 = *(const float4*)(&red_z[row][0]);
    float4 z1 = *(const float4*)(&red_z[row][4]);
    float z = z0.x + z0.y + z0.z + z0.w + z1.x + z1.y + z1.z + z1.w;
    invz_s[row] = 1.0f / z;
    float pmx = mr;
    #pragma unroll
    for (int o = 1; o < 64; o <<= 1) pmx = fmaxf(pmx, __shfl_xor(pmx, o));
    float wg = __expf(mr - pmx);
    wgt_s[row] = wg;
    float zs = wg;
    #pragma unroll
    for (int o = 1; o < 64; o <<= 1) zs += __shfl_xor(zs, o);
    if (ln == 0) { pm_g[b * 64 + tile] = pmx; z_g[b * 64 + tile] = zs; }
  }

  // ---- GEMM2: c2q = P(64x512) @ q(512x256); waves split d in 32s ----
  f32x4 o2[4][2];
  #pragma unroll
  for (int m = 0; m < 4; ++m)
    #pragma unroll
    for (int n = 0; n < 2; ++n) o2[m][n] = (f32x4){0.f, 0.f, 0.f, 0.f};

  int dc = wv * 32;
  const u16* qtb = qTbf + (size_t)b * DD * QL + (size_t)(dc + lr) * QL + lg * 8;
  s16x8 bvn[2];
  #pragma unroll
  for (int n = 0; n < 2; ++n) bvn[n] = *(const s16x8*)(qtb + (size_t)(n * 16) * QL);
  #pragma unroll 4
  for (int kk = 0; kk < 16; ++kk) {
    s16x8 bvc[2];
    #pragma unroll
    for (int n = 0; n < 2; ++n) bvc[n] = bvn[n];
    if (kk < 15) {
      #pragma unroll
      for (int n = 0; n < 2; ++n)
        bvn[n] = *(const s16x8*)(qtb + (size_t)(n * 16) * QL + (kk + 1) * 32);
    }
    s16x8 pa[4];
    #pragma unroll
    for (int m = 0; m < 4; ++m)
      pa[m] = *(const s16x8*)(&pool[(m * 16 + lr) * 512 + ((kk * 32 + lg * 8) ^ aswz)]);
    #pragma unroll
    for (int m = 0; m < 4; ++m)
      #pragma unroll
      for (int n = 0; n < 2; ++n)
        o2[m][n] = __builtin_amdgcn_mfma_f32_16x16x32_bf16(pa[m], bvc[n], o2[m][n], 0, 0, 0);
  }
  __syncthreads();   // invz_s/wgt_s visible

  // ---- epilogue: segments 1 (c2q), 2 (c*c2q), q2c partial ----
  #pragma unroll
  for (int n = 0; n < 2; ++n) {
    int dcol = dc + n * 16 + lr;
    float psum = 0.f;
    #pragma unroll
    for (int m = 0; m < 4; ++m)
      #pragma unroll
      for (int rr = 0; rr < 4; ++rr) {
        int row = m * 16 + lg * 4 + rr;
        int grow = it0 + row;
        float c2q = o2[m][n][rr] * invz_s[row];
        float cv = c[((size_t)(b * CL + grow)) * DD + dcol];
        size_t ob = ((size_t)(b * CL + grow)) * (4 * DD);
        out[ob + DD + dcol] = c2q;
        out[ob + 2 * DD + dcol] = cv * c2q;
        psum += wgt_s[row] * cv;
      }
    psum += __shfl_xor(psum, 16);
    psum += __shfl_xor(psum, 32);
    if (ln < 16) part_g[((size_t)(b * 64 + tile)) * DD + dcol] = psum;
  }
}

// ---------------- K2: combine tile partials -> q2c ------------------------
__global__ __launch_bounds__(256) void q2c_reduce_k(
    const float* __restrict__ pm_g, const float* __restrict__ z_g,
    const float* __restrict__ part_g, float* __restrict__ q2c)
{
  __shared__ float wk[64];
  __shared__ float rm[4];
  __shared__ float rz[4];
  int b = blockIdx.x;
  int t = threadIdx.x;

  float p = (t < 64) ? pm_g[b * 64 + t] : -1e30f;
  float m = p;
  #pragma unroll
  for (int o = 1; o < 64; o <<= 1) m = fmaxf(m, __shfl_xor(m, o));
  if ((t & 63) == 0) rm[t >> 6] = m;
  __syncthreads();
  float M = fmaxf(fmaxf(rm[0], rm[1]), fmaxf(rm[2], rm[3]));

  float ew = (t < 64) ? __expf(p - M) : 0.f;
  float zi = (t < 64) ? ew * z_g[b * 64 + t] : 0.f;
  float s = zi;
  #pragma unroll
  for (int o = 1; o < 64; o <<= 1) s += __shfl_xor(s, o);
  if ((t & 63) == 0) rz[t >> 6] = s;
  __syncthreads();
  float Z = rz[0] + rz[1] + rz[2] + rz[3];

  if (t < 64) wk[t] = ew / Z;
  __syncthreads();

  float acc = 0.f;
  for (int k = 0; k < 64; ++k)
    acc += wk[k] * part_g[((size_t)(b * 64 + k)) * DD + t];
  q2c[b * DD + t] = acc;
}

// ---------------- K3: out segment 3 = c * q2c -----------------------------
__global__ __launch_bounds__(256) void seg3_k(
    const float* __restrict__ c, const float* __restrict__ q2c,
    float* __restrict__ out)
{
  size_t stride = (size_t)gridDim.x * 256;
  size_t total = (size_t)BB * CL * (DD / 4);  // float4 count
  for (size_t e = (size_t)blockIdx.x * 256 + threadIdx.x; e < total; e += stride) {
    int b = (int)(e >> 18);
    int rem = (int)(e & 262143);
    int i = rem >> 6;
    int dv = rem & 63;
    float4 cv = *(const float4*)(c + ((size_t)(b * CL + i)) * DD + dv * 4);
    float4 g  = *(const float4*)(q2c + b * DD + dv * 4);
    float4 r;
    r.x = cv.x * g.x; r.y = cv.y * g.y; r.z = cv.z * g.z; r.w = cv.w * g.w;
    *(float4*)(out + ((size_t)(b * CL + i)) * (4 * DD) + 3 * DD + dv * 4) = r;
  }
}

extern "C" void kernel_launch(void* const* d_in, const int* in_sizes, int n_in,
                              void* d_out, int out_size, void* d_ws, size_t ws_size,
                              hipStream_t stream) {
  const float* q = (const float*)d_in[0];
  const float* c = (const float*)d_in[1];
  const float* w = (const float*)d_in[2];
  float* out = (float*)d_out;
  char* ws = (char*)d_ws;

  u16*   qbf   = (u16*)(ws);                    // 2,097,152 B
  u16*   qTbf  = (u16*)(ws + 2097152);          // 2,097,152 B
  float* qw    = (float*)(ws + 4194304);        //    16,384 B
  float* pm    = (float*)(ws + 4210688);        //     2,048 B
  float* zb    = (float*)(ws + 4214784);        //     2,048 B
  float* part  = (float*)(ws + 4218880);        //   524,288 B
  float* q2c   = (float*)(ws + 5267456);        //     8,192 B

  prep_q_k<<<512, 256, 0, stream>>>(q, w, qbf, qTbf, qw);
  attn_main_k<<<512, 512, 0, stream>>>(c, w, qbf, qTbf, qw, pm, zb, part, out);
  q2c_reduce_k<<<8, 256, 0, stream>>>(pm, zb, part, q2c);
  seg3_k<<<2048, 256, 0, stream>>>(c, q2c, out);
}